// Round 5
// baseline (808.323 us; speedup 1.0000x reference)
//
#include <hip/hip_runtime.h>
#include <math.h>

#define NB 32
#define NS 4096
#define ND 512
#define NU 128

typedef __bf16 bf16x8 __attribute__((ext_vector_type(8)));
typedef unsigned short u16x8 __attribute__((ext_vector_type(8)));
typedef float f32x4 __attribute__((ext_vector_type(4)));

union FragCvt { u16x8 u; bf16x8 b; };

__device__ inline unsigned short f2bf(float x) {
  union { float f; unsigned u; } v; v.f = x;
  return (unsigned short)((v.u + 0x7FFFu + ((v.u >> 16) & 1u)) >> 16);
}
__device__ inline float bf2f(unsigned int bits16) {  // low 16 bits are bf16
  union { unsigned u; float f; } v; v.u = bits16 << 16;
  return v.f;
}
__device__ inline float fast_tanh(float x) {
  x = fminf(9.f, fmaxf(-9.f, x));
  float e2 = __expf(2.f * x);
  return (e2 - 1.f) * __builtin_amdgcn_rcpf(e2 + 1.f);
}
// B-tile XOR swizzle (within an 8KB kt-tile): spread 128B-rows across 16B slots
__device__ inline int bswz(int byte) { return byte ^ (((byte >> 7) & 7) << 4); }

// ---------------- prep: qb[b][u] += partial(query@W1) + b1 + b2 (split-K, qb pre-zeroed) ----------------
__global__ void prep_qb(const float* __restrict__ q, const float* __restrict__ W1,
                        const float* __restrict__ b1, const float* __restrict__ b2,
                        float* __restrict__ qb) {
  const int bb = blockIdx.x >> 4;
  const int kc = blockIdx.x & 15;
  const int u  = threadIdx.x & 127;
  const int dh = threadIdx.x >> 7;
  const int d0 = kc * 32 + dh * 16;
  const float* qr = q + bb * ND + d0;
  const float* w  = W1 + (size_t)d0 * NU + u;
  float s = (kc == 0 && dh == 0) ? (b1[u] + b2[u]) : 0.f;
  #pragma unroll
  for (int j = 0; j < 16; ++j) s += qr[j] * w[j * NU];
  atomicAdd(qb + bb * NU + u, s);
}

// ---------------- prep: W2 -> k-tile-major bf16: w2s[kt][u][k'] ----------------
__global__ void prep_w2s(const float* __restrict__ W2, unsigned short* __restrict__ w2s) {
  const int idx = blockIdx.x * 256 + threadIdx.x;   // 65536
  const int u = idx & 127;
  const int r = idx >> 7;
  const int k = r & 31, kt = r >> 5;
  w2s[kt * 4096 + u * 32 + k] = f2bf(W2[(size_t)(kt * 32 + k) * NU + u]);
}

// ---------------- fused: barrier-free streaming attention ----------------
// Full B (128KB bf16) resident in LDS, loaded once (1 barrier). Each wave owns 16 rows x
// all 128 cols: A read once from global (fp32->bf16 in regs, KEPT), scores/exp/L per-wave,
// context from in-register A via 4-step shuffle reduce-scatter. Zero barriers after load.
__global__ __launch_bounds__(512, 1) void fused_attn(
    const float* __restrict__ values,
    const float* __restrict__ qb,            // [NB][NU]
    const unsigned short* __restrict__ w2s,  // [16][128][32] bf16 bits
    const float* __restrict__ V,             // [NU]
    const float* __restrict__ bvp,           // [1]
    float* __restrict__ wout,                // [NB][NS] unnormalized e^s
    float* __restrict__ Cacc,                // [NB][ND] partial context (ws, zeroed)
    float* __restrict__ Lacc)                // [NB] partial denom (ws, zeroed)
{
  __shared__ unsigned short Bs[16 * 4096];   // 131072 B: 16 kt-tiles of 8KB, swizzled

  const int tid = threadIdx.x;
  const int blk = blockIdx.x;
  const int b = blk >> 4;                    // 16 blocks per batch
  const int pair = blk & 15;                 // each block: 2 chunks of 128 rows

  // ---- load full B into LDS (once) ----
  const uint4* w2s4 = (const uint4*)w2s;     // 8192 16B-slots
  #pragma unroll
  for (int i = 0; i < 16; ++i) {
    const int m = i * 512 + tid;
    const uint4 v = w2s4[m];
    *(uint4*)((char*)Bs + (m >> 9) * 8192 + bswz((m & 511) * 16)) = v;
  }
  __syncthreads();                           // the ONLY barrier

  const int wave = tid >> 6, lane = tid & 63;
  const int quad = lane >> 4, lidx = lane & 15;

  // per-lane swizzled B within-tile offsets (8 n-tiles)
  int boff[8];
  #pragma unroll
  for (int nt = 0; nt < 8; ++nt)
    boff[nt] = bswz((nt * 16 + lidx) * 64 + quad * 16);

  float qv[8], vv[8];
  #pragma unroll
  for (int nt = 0; nt < 8; ++nt) {
    qv[nt] = qb[b * NU + nt * 16 + lidx];
    vv[nt] = V[nt * 16 + lidx];
  }
  const float bv = *bvp;

  for (int c = 0; c < 2; ++c) {
    const int s0c = (pair * 2 + c) * 128;
    const int row = s0c + wave * 16 + lidx;        // this lane's A row
    const float* abase = values + ((size_t)b * NS + row) * ND + quad * 8;

    // ---- k-loop: A from global (kept in regs), B frags from LDS; no barriers ----
    f32x4 acc[8] = {{0.f,0.f,0.f,0.f},{0.f,0.f,0.f,0.f},{0.f,0.f,0.f,0.f},{0.f,0.f,0.f,0.f},
                    {0.f,0.f,0.f,0.f},{0.f,0.f,0.f,0.f},{0.f,0.f,0.f,0.f},{0.f,0.f,0.f,0.f}};
    FragCvt a[16];
    #pragma unroll
    for (int kt = 0; kt < 16; ++kt) {
      const float4 a0 = *(const float4*)(abase + kt * 32);
      const float4 a1 = *(const float4*)(abase + kt * 32 + 4);
      a[kt].b[0] = (__bf16)a0.x; a[kt].b[1] = (__bf16)a0.y;
      a[kt].b[2] = (__bf16)a0.z; a[kt].b[3] = (__bf16)a0.w;
      a[kt].b[4] = (__bf16)a1.x; a[kt].b[5] = (__bf16)a1.y;
      a[kt].b[6] = (__bf16)a1.z; a[kt].b[7] = (__bf16)a1.w;
      const char* bt = (const char*)Bs + kt * 8192;
      #pragma unroll
      for (int nt = 0; nt < 8; ++nt) {
        FragCvt bf; bf.u = *(const u16x8*)(bt + boff[nt]);
        acc[nt] = __builtin_amdgcn_mfma_f32_16x16x32_bf16(a[kt].b, bf.b, acc[nt], 0, 0, 0);
      }
    }

    // ---- scores: tanh + dot(V); C layout: row_local = quad*4+r, col = nt*16+lidx ----
    float part[4] = {0.f, 0.f, 0.f, 0.f};
    #pragma unroll
    for (int nt = 0; nt < 8; ++nt) {
      #pragma unroll
      for (int r = 0; r < 4; ++r)
        part[r] += fast_tanh(acc[nt][r] + qv[nt]) * vv[nt];
    }
    #pragma unroll
    for (int m = 1; m <= 8; m <<= 1) {
      #pragma unroll
      for (int r = 0; r < 4; ++r) part[r] += __shfl_xor(part[r], m, 64);
    }
    // redistribute: lane wants score for row_local = lidx (held at lane (lidx>>2)*16+lidx, reg lidx&3)
    const int r3 = lidx & 3;
    float tmp = (r3 == 0) ? part[0] : (r3 == 1) ? part[1] : (r3 == 2) ? part[2] : part[3];
    const float sc = __shfl(tmp, (lidx >> 2) * 16 + lidx, 64);
    const float e = __expf(sc + bv);                 // |sc| bounded by tanh * ||V||_1
    if (quad == 0) wout[(size_t)b * NS + s0c + wave * 16 + lidx] = e;
    float es = e;
    es += __shfl_xor(es, 1, 64); es += __shfl_xor(es, 2, 64);
    es += __shfl_xor(es, 4, 64); es += __shfl_xor(es, 8, 64);
    if (lane == 0) atomicAdd(Lacc + b, es);

    // ---- context from in-register A: reduce-scatter e*a over the 16 row-lanes ----
    // after 4 steps lane holds 8 summed cols: col = lidx*32 + quad*8 + j
    const bool h0 = lidx & 1, h1 = lidx & 2, h2 = lidx & 4, h3 = lidx & 8;
    float cA[8][8];
    #pragma unroll
    for (int k = 0; k < 8; ++k) {
      #pragma unroll
      for (int j = 0; j < 8; ++j) {
        const float lo = e * bf2f(a[2 * k].u[j]);
        const float hi = e * bf2f(a[2 * k + 1].u[j]);
        const float mine = h0 ? hi : lo;
        const float oth  = h0 ? lo : hi;
        cA[k][j] = mine + __shfl_xor(oth, 1, 64);
      }
    }
    float cB[4][8];
    #pragma unroll
    for (int k = 0; k < 4; ++k) {
      #pragma unroll
      for (int j = 0; j < 8; ++j) {
        const float mine = h1 ? cA[2 * k + 1][j] : cA[2 * k][j];
        const float oth  = h1 ? cA[2 * k][j] : cA[2 * k + 1][j];
        cB[k][j] = mine + __shfl_xor(oth, 2, 64);
      }
    }
    float cC[2][8];
    #pragma unroll
    for (int k = 0; k < 2; ++k) {
      #pragma unroll
      for (int j = 0; j < 8; ++j) {
        const float mine = h2 ? cB[2 * k + 1][j] : cB[2 * k][j];
        const float oth  = h2 ? cB[2 * k][j] : cB[2 * k + 1][j];
        cC[k][j] = mine + __shfl_xor(oth, 4, 64);
      }
    }
    float cD[8];
    #pragma unroll
    for (int j = 0; j < 8; ++j) {
      const float mine = h3 ? cC[1][j] : cC[0][j];
      const float oth  = h3 ? cC[0][j] : cC[1][j];
      cD[j] = mine + __shfl_xor(oth, 8, 64);
    }
    #pragma unroll
    for (int j = 0; j < 8; ++j)
      atomicAdd(Cacc + b * ND + lidx * 32 + quad * 8 + j, cD[j]);
  }
}

// ---------------- finalize: divide by denom ----------------
__global__ void finalize(const float* __restrict__ Cacc, const float* __restrict__ Lacc,
                         float* __restrict__ out) {
  int idx = blockIdx.x * 256 + threadIdx.x;   // 147456 total
  if (idx < NB * ND) {
    int b = idx >> 9;
    out[idx] = Cacc[idx] / Lacc[b];
  } else {
    int j = idx - NB * ND;
    int b = j >> 12;
    out[idx] = out[idx] / Lacc[b];
  }
}

extern "C" void kernel_launch(void* const* d_in, const int* in_sizes, int n_in,
                              void* d_out, int out_size, void* d_ws, size_t ws_size,
                              hipStream_t stream) {
  const float* query  = (const float*)d_in[0];
  const float* values = (const float*)d_in[1];
  const float* W1     = (const float*)d_in[2];
  const float* b1     = (const float*)d_in[3];
  const float* W2     = (const float*)d_in[4];
  const float* b2     = (const float*)d_in[5];
  const float* V      = (const float*)d_in[6];
  const float* bv     = (const float*)d_in[7];
  float* out = (float*)d_out;

  char* ws = (char*)d_ws;
  float* Cacc = (float*)ws;                               // 65536 B
  float* Lacc = (float*)(ws + 65536);                     // 128 B
  float* qb   = (float*)(ws + 66048);                     // 16384 B
  unsigned short* w2s = (unsigned short*)(ws + 66048 + 16384);  // 131072 B

  hipMemsetAsync(ws, 0, 66048 + 16384, stream);           // zero Cacc + Lacc + qb

  prep_qb <<<NB * 16, 256, 0, stream>>>(query, W1, b1, b2, qb);
  prep_w2s<<<256, 256, 0, stream>>>(W2, w2s);
  fused_attn<<<512, 512, 0, stream>>>(values, qb, w2s, V, bv,
                                      out + NB * ND, Cacc, Lacc);
  finalize<<<(NB * ND + NB * NS) / 256, 256, 0, stream>>>(Cacc, Lacc, out);
}

// Round 6
// 451.196 us; speedup vs baseline: 1.7915x; 1.7915x over previous
//
#include <hip/hip_runtime.h>
#include <math.h>

#define NB 32
#define NS 4096
#define ND 512
#define NU 128

typedef __bf16 bf16x8 __attribute__((ext_vector_type(8)));
typedef unsigned short u16x8 __attribute__((ext_vector_type(8)));
typedef float f32x4 __attribute__((ext_vector_type(4)));

union FragCvt { u16x8 u; bf16x8 b; };

__device__ inline unsigned short f2bf(float x) {
  union { float f; unsigned u; } v; v.f = x;
  return (unsigned short)((v.u + 0x7FFFu + ((v.u >> 16) & 1u)) >> 16);
}
__device__ inline float fast_tanh(float x) {
  x = fminf(9.f, fmaxf(-9.f, x));
  float e2 = __expf(2.f * x);
  return (e2 - 1.f) * __builtin_amdgcn_rcpf(e2 + 1.f);
}
// B-tile XOR swizzle (within an 8KB kt-tile): spread 128B-rows across 16B slots
__device__ inline int bswz(int byte) { return byte ^ (((byte >> 7) & 7) << 4); }

// ---------------- prep: qb[b][u] += partial(query@W1) + b1 + b2 (split-K, qb pre-zeroed) ----------------
__global__ void prep_qb(const float* __restrict__ q, const float* __restrict__ W1,
                        const float* __restrict__ b1, const float* __restrict__ b2,
                        float* __restrict__ qb) {
  const int bb = blockIdx.x >> 4;
  const int kc = blockIdx.x & 15;
  const int u  = threadIdx.x & 127;
  const int dh = threadIdx.x >> 7;
  const int d0 = kc * 32 + dh * 16;
  const float* qr = q + bb * ND + d0;
  const float* w  = W1 + (size_t)d0 * NU + u;
  float s = (kc == 0 && dh == 0) ? (b1[u] + b2[u]) : 0.f;
  #pragma unroll
  for (int j = 0; j < 16; ++j) s += qr[j] * w[j * NU];
  atomicAdd(qb + bb * NU + u, s);
}

// ---------------- prep: W2 -> k-tile-major bf16: w2s[kt][u][k'] ----------------
__global__ void prep_w2s(const float* __restrict__ W2, unsigned short* __restrict__ w2s) {
  const int idx = blockIdx.x * 256 + threadIdx.x;   // 65536
  const int u = idx & 127;
  const int r = idx >> 7;
  const int k = r & 31, kt = r >> 5;
  w2s[kt * 4096 + u * 32 + k] = f2bf(W2[(size_t)(kt * 32 + k) * NU + u]);
}

// ---------------- fused: barrier-light streaming attention ----------------
// Full B (128KB bf16) resident in LDS, loaded once (1 barrier). Each wave owns 16 rows x
// all 128 cols: A streamed from global (fp32->bf16 in regs, NOT retained). Scores/exp/L
// per-wave; e broadcast via dbuf LDS (1 barrier/chunk); context = column-per-thread
// coalesced re-read of the L2-hot chunk. No register-array retention -> no spill.
__global__ __launch_bounds__(512, 1) void fused_attn(
    const float* __restrict__ values,
    const float* __restrict__ qb,            // [NB][NU]
    const unsigned short* __restrict__ w2s,  // [16][128][32] bf16 bits
    const float* __restrict__ V,             // [NU]
    const float* __restrict__ bvp,           // [1]
    float* __restrict__ wout,                // [NB][NS] unnormalized e^s
    float* __restrict__ Cacc,                // [NB][ND] partial context (ws, zeroed)
    float* __restrict__ Lacc)                // [NB] partial denom (ws, zeroed)
{
  __shared__ unsigned short Bs[16 * 4096];   // 131072 B: 16 kt-tiles of 8KB, swizzled
  __shared__ float e_lds[2][128];            // dbuf: chunk's softmax numerators

  const int tid = threadIdx.x;
  const int blk = blockIdx.x;
  const int b = blk >> 4;                    // 16 blocks per batch
  const int pair = blk & 15;                 // each block: 2 chunks of 128 rows

  // ---- load full B into LDS (once) ----
  const uint4* w2s4 = (const uint4*)w2s;     // 8192 16B-slots
  #pragma unroll
  for (int i = 0; i < 16; ++i) {
    const int m = i * 512 + tid;
    const uint4 v = w2s4[m];
    *(uint4*)((char*)Bs + (m >> 9) * 8192 + bswz((m & 511) * 16)) = v;
  }
  __syncthreads();

  const int wave = tid >> 6, lane = tid & 63;
  const int quad = lane >> 4, lidx = lane & 15;

  // per-lane swizzled B within-tile offsets (8 n-tiles)
  int boff[8];
  #pragma unroll
  for (int nt = 0; nt < 8; ++nt)
    boff[nt] = bswz((nt * 16 + lidx) * 64 + quad * 16);

  float qv[8], vv[8];
  #pragma unroll
  for (int nt = 0; nt < 8; ++nt) {
    qv[nt] = qb[b * NU + nt * 16 + lidx];
    vv[nt] = V[nt * 16 + lidx];
  }
  const float bv = *bvp;

  for (int c = 0; c < 2; ++c) {
    const int s0c = (pair * 2 + c) * 128;
    const int row = s0c + wave * 16 + lidx;        // this lane's A row
    const float* abase = values + ((size_t)b * NS + row) * ND + quad * 8;

    // ---- k-loop: A streamed from global, B frags from LDS; no barriers ----
    f32x4 acc[8] = {{0.f,0.f,0.f,0.f},{0.f,0.f,0.f,0.f},{0.f,0.f,0.f,0.f},{0.f,0.f,0.f,0.f},
                    {0.f,0.f,0.f,0.f},{0.f,0.f,0.f,0.f},{0.f,0.f,0.f,0.f},{0.f,0.f,0.f,0.f}};
    #pragma unroll 4
    for (int kt = 0; kt < 16; ++kt) {
      const float4 a0 = *(const float4*)(abase + kt * 32);
      const float4 a1 = *(const float4*)(abase + kt * 32 + 4);
      FragCvt a;
      a.b[0] = (__bf16)a0.x; a.b[1] = (__bf16)a0.y;
      a.b[2] = (__bf16)a0.z; a.b[3] = (__bf16)a0.w;
      a.b[4] = (__bf16)a1.x; a.b[5] = (__bf16)a1.y;
      a.b[6] = (__bf16)a1.z; a.b[7] = (__bf16)a1.w;
      const char* bt = (const char*)Bs + kt * 8192;
      #pragma unroll
      for (int nt = 0; nt < 8; ++nt) {
        FragCvt bf; bf.u = *(const u16x8*)(bt + boff[nt]);
        acc[nt] = __builtin_amdgcn_mfma_f32_16x16x32_bf16(a.b, bf.b, acc[nt], 0, 0, 0);
      }
    }

    // ---- scores: tanh + dot(V); C layout: row_local = quad*4+r, col = nt*16+lidx ----
    float part[4] = {0.f, 0.f, 0.f, 0.f};
    #pragma unroll
    for (int nt = 0; nt < 8; ++nt) {
      #pragma unroll
      for (int r = 0; r < 4; ++r)
        part[r] += fast_tanh(acc[nt][r] + qv[nt]) * vv[nt];
    }
    #pragma unroll
    for (int m = 1; m <= 8; m <<= 1) {
      #pragma unroll
      for (int r = 0; r < 4; ++r) part[r] += __shfl_xor(part[r], m, 64);
    }
    // redistribute: lane wants score for row_local = lidx (held in quad lidx>>2, reg lidx&3)
    const int r3 = lidx & 3;
    float tmp = (r3 == 0) ? part[0] : (r3 == 1) ? part[1] : (r3 == 2) ? part[2] : part[3];
    const float sc = __shfl(tmp, (lidx >> 2) * 16 + lidx, 64);
    const float e = __expf(sc + bv);                 // |sc| bounded by tanh * ||V||_1
    if (quad == 0) {
      wout[(size_t)b * NS + s0c + wave * 16 + lidx] = e;
      e_lds[c][wave * 16 + lidx] = e;
    }
    float es = e;
    es += __shfl_xor(es, 1, 64); es += __shfl_xor(es, 2, 64);
    es += __shfl_xor(es, 4, 64); es += __shfl_xor(es, 8, 64);
    if (lane == 0) atomicAdd(Lacc + b, es);

    __syncthreads();   // e_lds[c] complete for all 128 rows

    // ---- context: column-per-thread coalesced re-read of the L2-hot chunk ----
    const float* vcol = values + ((size_t)b * NS + s0c) * ND + tid;
    float csum = 0.f;
    #pragma unroll 8
    for (int r = 0; r < 128; ++r)
      csum += e_lds[c][r] * vcol[(size_t)r * ND];
    atomicAdd(Cacc + b * ND + tid, csum);
    // no trailing barrier: chunk c+1 writes e_lds[c^1] (dbuf), Bs is read-only
  }
}

// ---------------- finalize: divide by denom ----------------
__global__ void finalize(const float* __restrict__ Cacc, const float* __restrict__ Lacc,
                         float* __restrict__ out) {
  int idx = blockIdx.x * 256 + threadIdx.x;   // 147456 total
  if (idx < NB * ND) {
    int b = idx >> 9;
    out[idx] = Cacc[idx] / Lacc[b];
  } else {
    int j = idx - NB * ND;
    int b = j >> 12;
    out[idx] = out[idx] / Lacc[b];
  }
}

extern "C" void kernel_launch(void* const* d_in, const int* in_sizes, int n_in,
                              void* d_out, int out_size, void* d_ws, size_t ws_size,
                              hipStream_t stream) {
  const float* query  = (const float*)d_in[0];
  const float* values = (const float*)d_in[1];
  const float* W1     = (const float*)d_in[2];
  const float* b1     = (const float*)d_in[3];
  const float* W2     = (const float*)d_in[4];
  const float* b2     = (const float*)d_in[5];
  const float* V      = (const float*)d_in[6];
  const float* bv     = (const float*)d_in[7];
  float* out = (float*)d_out;

  char* ws = (char*)d_ws;
  float* Cacc = (float*)ws;                               // 65536 B
  float* Lacc = (float*)(ws + 65536);                     // 128 B
  float* qb   = (float*)(ws + 66048);                     // 16384 B
  unsigned short* w2s = (unsigned short*)(ws + 66048 + 16384);  // 131072 B

  hipMemsetAsync(ws, 0, 66048 + 16384, stream);           // zero Cacc + Lacc + qb

  prep_qb <<<NB * 16, 256, 0, stream>>>(query, W1, b1, b2, qb);
  prep_w2s<<<256, 256, 0, stream>>>(W2, w2s);
  fused_attn<<<512, 512, 0, stream>>>(values, qb, w2s, V, bv,
                                      out + NB * ND, Cacc, Lacc);
  finalize<<<(NB * ND + NB * NS) / 256, 256, 0, stream>>>(Cacc, Lacc, out);
}

// Round 7
// 443.219 us; speedup vs baseline: 1.8238x; 1.0180x over previous
//
#include <hip/hip_runtime.h>
#include <math.h>

#define NB 32
#define NS 4096
#define ND 512
#define NU 128

typedef __bf16 bf16x8 __attribute__((ext_vector_type(8)));
typedef unsigned short u16x8 __attribute__((ext_vector_type(8)));
typedef float f32x4 __attribute__((ext_vector_type(4)));

union FragCvt { u16x8 u; bf16x8 b; };

__device__ inline unsigned short f2bf(float x) {
  union { float f; unsigned u; } v; v.f = x;
  return (unsigned short)((v.u + 0x7FFFu + ((v.u >> 16) & 1u)) >> 16);
}
__device__ inline float fast_tanh(float x) {
  x = fminf(9.f, fmaxf(-9.f, x));
  float e2 = __expf(2.f * x);
  return (e2 - 1.f) * __builtin_amdgcn_rcpf(e2 + 1.f);
}
// B-tile XOR swizzle (within an 8KB kt-tile): spread 128B-rows across 16B slots
__device__ inline int bswz(int byte) { return byte ^ (((byte >> 7) & 7) << 4); }

// ---------------- prep: qb[b][u] += partial(query@W1) + b1 + b2 (split-K, qb pre-zeroed) ----------------
__global__ void prep_qb(const float* __restrict__ q, const float* __restrict__ W1,
                        const float* __restrict__ b1, const float* __restrict__ b2,
                        float* __restrict__ qb) {
  const int bb = blockIdx.x >> 4;
  const int kc = blockIdx.x & 15;
  const int u  = threadIdx.x & 127;
  const int dh = threadIdx.x >> 7;
  const int d0 = kc * 32 + dh * 16;
  const float* qr = q + bb * ND + d0;
  const float* w  = W1 + (size_t)d0 * NU + u;
  float s = (kc == 0 && dh == 0) ? (b1[u] + b2[u]) : 0.f;
  #pragma unroll
  for (int j = 0; j < 16; ++j) s += qr[j] * w[j * NU];
  atomicAdd(qb + bb * NU + u, s);
}

// ---------------- prep: W2 -> k-tile-major bf16: w2s[kt][u][k'] ----------------
__global__ void prep_w2s(const float* __restrict__ W2, unsigned short* __restrict__ w2s) {
  const int idx = blockIdx.x * 256 + threadIdx.x;   // 65536
  const int u = idx & 127;
  const int r = idx >> 7;
  const int k = r & 31, kt = r >> 5;
  w2s[kt * 4096 + u * 32 + k] = f2bf(W2[(size_t)(kt * 32 + k) * NU + u]);
}

// ---------------- fused: barrier-light streaming attention, 16 waves sharing one B ----------------
// 1024-thread block = two independent 8-wave halves sharing the single LDS-resident B
// (128KB, loaded once). 4 waves/SIMD (vs 2) to overlap L1-line processing, LDS reads,
// VALU and HBM latency. Each half: waves own 16 rows x all 128 cols; A streamed from
// global (fp32->bf16 in regs, not retained); e via per-half dbuf LDS; context =
// float4 column re-read of the L2-hot chunk.
__global__ __launch_bounds__(1024, 1) void fused_attn(
    const float* __restrict__ values,
    const float* __restrict__ qb,            // [NB][NU]
    const unsigned short* __restrict__ w2s,  // [16][128][32] bf16 bits
    const float* __restrict__ V,             // [NU]
    const float* __restrict__ bvp,           // [1]
    float* __restrict__ wout,                // [NB][NS] unnormalized e^s
    float* __restrict__ Cacc,                // [NB][ND] partial context (ws, zeroed)
    float* __restrict__ Lacc)                // [NB] partial denom (ws, zeroed)
{
  __shared__ unsigned short Bs[16 * 4096];   // 131072 B: 16 kt-tiles of 8KB, swizzled
  __shared__ float e_lds[2][2][128];         // [half][chunk-buf][row]

  const int tid = threadIdx.x;
  const int blk = blockIdx.x;                // 256 blocks
  const int b = blk >> 3;                    // 8 blocks per batch
  const int eighth = blk & 7;                // each block: 4 chunks of 128 rows (2 per half)

  // ---- load full B into LDS (once) ----
  const uint4* w2s4 = (const uint4*)w2s;     // 8192 16B-slots
  #pragma unroll
  for (int i = 0; i < 8; ++i) {
    const int m = i * 1024 + tid;
    const uint4 v = w2s4[m];
    *(uint4*)((char*)Bs + (m >> 9) * 8192 + bswz((m & 511) * 16)) = v;
  }
  __syncthreads();

  const int wave = tid >> 6, lane = tid & 63;
  const int quad = lane >> 4, lidx = lane & 15;
  const int h = wave >> 3;                   // half id
  const int wl = wave & 7;                   // wave-in-half

  // per-lane swizzled B within-tile offsets (8 n-tiles)
  int boff[8];
  #pragma unroll
  for (int nt = 0; nt < 8; ++nt)
    boff[nt] = bswz((nt * 16 + lidx) * 64 + quad * 16);

  float qv[8], vv[8];
  #pragma unroll
  for (int nt = 0; nt < 8; ++nt) {
    qv[nt] = qb[b * NU + nt * 16 + lidx];
    vv[nt] = V[nt * 16 + lidx];
  }
  const float bv = *bvp;

  for (int c = 0; c < 2; ++c) {
    const int chunk = eighth * 4 + h * 2 + c;
    const int s0c = chunk * 128;
    const int row = s0c + wl * 16 + lidx;          // this lane's A row
    const float* abase = values + ((size_t)b * NS + row) * ND + quad * 8;

    // ---- k-loop: A streamed from global, B frags from LDS; no barriers ----
    f32x4 acc[8] = {{0.f,0.f,0.f,0.f},{0.f,0.f,0.f,0.f},{0.f,0.f,0.f,0.f},{0.f,0.f,0.f,0.f},
                    {0.f,0.f,0.f,0.f},{0.f,0.f,0.f,0.f},{0.f,0.f,0.f,0.f},{0.f,0.f,0.f,0.f}};
    #pragma unroll 4
    for (int kt = 0; kt < 16; ++kt) {
      const float4 a0 = *(const float4*)(abase + kt * 32);
      const float4 a1 = *(const float4*)(abase + kt * 32 + 4);
      FragCvt a;
      a.b[0] = (__bf16)a0.x; a.b[1] = (__bf16)a0.y;
      a.b[2] = (__bf16)a0.z; a.b[3] = (__bf16)a0.w;
      a.b[4] = (__bf16)a1.x; a.b[5] = (__bf16)a1.y;
      a.b[6] = (__bf16)a1.z; a.b[7] = (__bf16)a1.w;
      const char* bt = (const char*)Bs + kt * 8192;
      #pragma unroll
      for (int nt = 0; nt < 8; ++nt) {
        FragCvt bf; bf.u = *(const u16x8*)(bt + boff[nt]);
        acc[nt] = __builtin_amdgcn_mfma_f32_16x16x32_bf16(a.b, bf.b, acc[nt], 0, 0, 0);
      }
    }

    // ---- scores: tanh + dot(V); C layout: row_local = quad*4+r, col = nt*16+lidx ----
    float part[4] = {0.f, 0.f, 0.f, 0.f};
    #pragma unroll
    for (int nt = 0; nt < 8; ++nt) {
      #pragma unroll
      for (int r = 0; r < 4; ++r)
        part[r] += fast_tanh(acc[nt][r] + qv[nt]) * vv[nt];
    }
    #pragma unroll
    for (int m = 1; m <= 8; m <<= 1) {
      #pragma unroll
      for (int r = 0; r < 4; ++r) part[r] += __shfl_xor(part[r], m, 64);
    }
    // redistribute: lane wants score for row_local = lidx (held in quad lidx>>2, reg lidx&3)
    const int r3 = lidx & 3;
    float tmp = (r3 == 0) ? part[0] : (r3 == 1) ? part[1] : (r3 == 2) ? part[2] : part[3];
    const float sc = __shfl(tmp, (lidx >> 2) * 16 + lidx, 64);
    const float e = __expf(sc + bv);                 // |sc| bounded by tanh * ||V||_1
    if (quad == 0) {
      wout[(size_t)b * NS + s0c + wl * 16 + lidx] = e;
      e_lds[h][c][wl * 16 + lidx] = e;
    }
    float es = e;
    es += __shfl_xor(es, 1, 64); es += __shfl_xor(es, 2, 64);
    es += __shfl_xor(es, 4, 64); es += __shfl_xor(es, 8, 64);
    if (lane == 0) atomicAdd(Lacc + b, es);

    __syncthreads();   // e_lds[h][c] complete (both halves hit equal barrier counts)

    // ---- context: float4 column re-read of the L2-hot chunk ----
    const int col4 = tid & 127;                    // 128 float4-columns
    const int rg = (tid >> 7) & 3;                 // 4 row-groups of 32 within the half
    const float* vb = values + ((size_t)b * NS + s0c + rg * 32) * ND + col4 * 4;
    float4 cs = {0.f, 0.f, 0.f, 0.f};
    #pragma unroll 8
    for (int r = 0; r < 32; ++r) {
      const float w = e_lds[h][c][rg * 32 + r];
      const float4 v = *(const float4*)(vb + (size_t)r * ND);
      cs.x += w * v.x; cs.y += w * v.y; cs.z += w * v.z; cs.w += w * v.w;
    }
    atomicAdd(Cacc + b * ND + col4 * 4 + 0, cs.x);
    atomicAdd(Cacc + b * ND + col4 * 4 + 1, cs.y);
    atomicAdd(Cacc + b * ND + col4 * 4 + 2, cs.z);
    atomicAdd(Cacc + b * ND + col4 * 4 + 3, cs.w);
    // no trailing barrier: chunk c+1 uses e_lds[h][c^1] (dbuf); Bs is read-only
  }
}

// ---------------- finalize: divide by denom ----------------
__global__ void finalize(const float* __restrict__ Cacc, const float* __restrict__ Lacc,
                         float* __restrict__ out) {
  int idx = blockIdx.x * 256 + threadIdx.x;   // 147456 total
  if (idx < NB * ND) {
    int b = idx >> 9;
    out[idx] = Cacc[idx] / Lacc[b];
  } else {
    int j = idx - NB * ND;
    int b = j >> 12;
    out[idx] = out[idx] / Lacc[b];
  }
}

extern "C" void kernel_launch(void* const* d_in, const int* in_sizes, int n_in,
                              void* d_out, int out_size, void* d_ws, size_t ws_size,
                              hipStream_t stream) {
  const float* query  = (const float*)d_in[0];
  const float* values = (const float*)d_in[1];
  const float* W1     = (const float*)d_in[2];
  const float* b1     = (const float*)d_in[3];
  const float* W2     = (const float*)d_in[4];
  const float* b2     = (const float*)d_in[5];
  const float* V      = (const float*)d_in[6];
  const float* bv     = (const float*)d_in[7];
  float* out = (float*)d_out;

  char* ws = (char*)d_ws;
  float* Cacc = (float*)ws;                               // 65536 B
  float* Lacc = (float*)(ws + 65536);                     // 128 B
  float* qb   = (float*)(ws + 66048);                     // 16384 B
  unsigned short* w2s = (unsigned short*)(ws + 66048 + 16384);  // 131072 B

  hipMemsetAsync(ws, 0, 66048 + 16384, stream);           // zero Cacc + Lacc + qb

  prep_qb <<<NB * 16, 256, 0, stream>>>(query, W1, b1, b2, qb);
  prep_w2s<<<256, 256, 0, stream>>>(W2, w2s);
  fused_attn<<<NB * 8, 1024, 0, stream>>>(values, qb, w2s, V, bv,
                                          out + NB * ND, Cacc, Lacc);
  finalize<<<(NB * ND + NB * NS) / 256, 256, 0, stream>>>(Cacc, Lacc, out);
}